// Round 1
// baseline (103.076 us; speedup 1.0000x reference)
//
#include <hip/hip_runtime.h>

#define NBINS 10
#define C 10

constexpr int BLOCK = 256;
constexpr int GRID  = 2048;
constexpr int STR   = 11;   // LDS row stride (gcd(11,32)=1 -> spread banks)

__global__ __launch_bounds__(BLOCK) void ece_main(
    const float* __restrict__ probs,
    const int*   __restrict__ labels,
    double*       __restrict__ g_conf,
    unsigned int* __restrict__ g_cnt,
    unsigned int* __restrict__ g_cor,
    int n)
{
    __shared__ float        s_conf[BLOCK * STR];
    __shared__ unsigned int s_cnt [BLOCK * STR];
    __shared__ unsigned int s_cor [NBINS];

    const int tid  = threadIdx.x;
    const int base = tid * STR;

#pragma unroll
    for (int b = 0; b < NBINS; ++b) { s_conf[base + b] = 0.0f; s_cnt[base + b] = 0u; }
    if (tid < NBINS) s_cor[tid] = 0u;
    __syncthreads();

    for (int i = blockIdx.x * BLOCK + tid; i < n; i += GRID * BLOCK) {
        const float2* r = reinterpret_cast<const float2*>(probs + (size_t)i * C);
        float2 v0 = r[0], v1 = r[1], v2 = r[2], v3 = r[3], v4 = r[4];
        float p[C];
        p[0]=v0.x; p[1]=v0.y; p[2]=v1.x; p[3]=v1.y; p[4]=v2.x;
        p[5]=v2.y; p[6]=v3.x; p[7]=v3.y; p[8]=v4.x; p[9]=v4.y;

        const int lbl = labels[i];

        // argmax (first occurrence on ties, matching jnp.argmax)
        float mx = p[0]; int arg = 0;
#pragma unroll
        for (int j = 1; j < C; ++j) {
            if (p[j] > mx) { mx = p[j]; arg = j; }
        }

        float lv = p[0];
#pragma unroll
        for (int j = 0; j < C; ++j) {
            lv = (j == lbl) ? p[j] : lv;   // static indexing only (no scratch)
            const float x = p[j];
            int idx = (int)ceilf(x * 10.0f) - 1;   // (e_j, e_{j+1}] -> j ; x<=0 -> -1
            if (idx >= 0) {
                idx = min(idx, NBINS - 1);
                s_cnt [base + idx] += 1u;
                s_conf[base + idx] += x;
            }
        }

        if (arg == lbl) {
            int idx = min((int)ceilf(lv * 10.0f) - 1, NBINS - 1);
            if (idx >= 0) atomicAdd(&s_cor[idx], 1u);
        }
    }
    __syncthreads();

    // tree-reduce the 256 privatized rows into row 0
    for (int off = BLOCK / 2; off > 0; off >>= 1) {
        if (tid < off) {
#pragma unroll
            for (int b = 0; b < NBINS; ++b) {
                s_conf[tid * STR + b] += s_conf[(tid + off) * STR + b];
                s_cnt [tid * STR + b] += s_cnt [(tid + off) * STR + b];
            }
        }
        __syncthreads();
    }

    if (tid < NBINS) {
        atomicAdd(&g_conf[tid], (double)s_conf[tid]);  // row 0, bin tid
        atomicAdd(&g_cnt [tid], s_cnt[tid]);
        atomicAdd(&g_cor [tid], s_cor[tid]);
    }
}

__global__ void ece_final(const double* __restrict__ g_conf,
                          const unsigned int* __restrict__ g_cnt,
                          const unsigned int* __restrict__ g_cor,
                          float* __restrict__ out)
{
    if (threadIdx.x == 0 && blockIdx.x == 0) {
        const float edges[11] = {0.0f,0.1f,0.2f,0.3f,0.4f,0.5f,
                                 0.6f,0.7f,0.8f,0.9f,1.0f};
        double total = 0.0;
        for (int j = 0; j < NBINS; ++j) total += (double)g_cnt[j];
        double ece = 0.0;
        for (int j = 0; j < NBINS; ++j) {
            const double c  = (double)g_cnt[j];
            const double bc = g_conf[j] / c;
            const double ba = (double)g_cor[j] / c;
            ece += fabs(bc - ba) * c;
            out[1 + j]  = edges[j + 1] - 0.05f;   // bin centers, float32 arithmetic
            out[11 + j] = (float)ba;              // bin accuracy
        }
        out[0] = (float)(ece / total);
    }
}

extern "C" void kernel_launch(void* const* d_in, const int* in_sizes, int n_in,
                              void* d_out, int out_size, void* d_ws, size_t ws_size,
                              hipStream_t stream)
{
    const float* probs  = (const float*)d_in[0];
    const int*   labels = (const int*)  d_in[1];
    float*       out    = (float*)d_out;
    const int n = in_sizes[1];   // labels count = N_SAMPLES

    // workspace layout: [0,80) double conf_sum[10] | [80,120) uint cnt[10] | [120,160) uint cor[10]
    double*       g_conf = (double*)d_ws;
    unsigned int* g_cnt  = (unsigned int*)((char*)d_ws + 80);
    unsigned int* g_cor  = (unsigned int*)((char*)d_ws + 120);

    hipMemsetAsync(d_ws, 0, 160, stream);   // ws is not re-poisoned between replays
    ece_main<<<GRID, BLOCK, 0, stream>>>(probs, labels, g_conf, g_cnt, g_cor, n);
    ece_final<<<1, 64, 0, stream>>>(g_conf, g_cnt, g_cor, out);
}